// Round 8
// baseline (147.934 us; speedup 1.0000x reference)
//
#include <hip/hip_runtime.h>
#include <hip/hip_bf16.h>
#include <hip/hip_fp8.h>

// ContrastiveLoss (SimCLR InfoNCE): N=8192, D=1024, T=0.1
// nll[i] = -logit[i, (i+N/2)%N] + logsumexp_j(logit[i,j]), diag masked out
// logit = cos_sim / T; out = mean(nll)
//
// Identities:
//  - zn_i = z_i * sqrt(10*log2e)/||z_i||  =>  dot d = logit*log2e and
//    exp(logit-10) = 2^(d - 10*log2e) -> raw v_exp_f32.
//  - logit in [-10,10] => FIXED-offset logsumexp; masked diag term == 0.
//  - Gram symmetric: upper-tri 256x256 supertiles (528 of 1024); off-diag
//    tile (I,J) adds exp row-sums to rows of I, col-sums to rows of J.
//  - positive-pair logits: J == I+16 supertiles, local col == local row.
//  - MX-scaled fp8 K=128 MFMA with all scales = 1.0 (2x bf16 rate).
//
// R20: 256x256 supertiles (528 tiles, was 2080 at 128x128). Evidence chain:
// R12-R15/R18 (5 schedules) neutral; R17 L2-ordering -14% then re-pinned at
// ~15.4 B/cy/CU staging; R16/R19 reg-staging DIED of register spill both
// times (launch_bounds(256,3) unified budget 170 < 148+32). Conclusion: a
// per-CU staging-throughput cap ~16 B/cy binds regardless of mechanism or
// schedule. Robust lever: halve staged bytes per output -- (256+256)/256^2
// vs (128+128)/128^2 = 2x fewer bytes (532->264 MB), also 4x fewer tile
// epilogues and 2x fewer barriers per output. Keeps the PROVEN pieces:
// gload_lds staging, XOR swizzle (global-side), supercell L2 order (4x4
// cells over the 32x32 supertile triangle, snake, 8x66 XCD chunks), fixed-
// offset LSE epilogue. 512 thr / 8 waves (2Mx4N), wave = 128x64 out, acc
// 128 AGPR + ~70 arch VGPR fits 256 budget (launch_bounds(512,2)); LDS
// 2x32KB A + 2x32KB B + 6KB red = 134KB (1 block/CU; occupancy was proven
// a non-factor R11-R13). One __syncthreads per phase (classic dbuf).
// Predicted: staged/CU 1.03MB @ ~15.4 B/cy -> gemm 30-35us, MfmaUtil
// 40-50%, WRITE ~19MB (no spill; check VGPR ~200), FETCH ~25MB.

#define N_ROWS 8192
#define DIM    1024
#define BM 256                         // supertile edge
#define BK 128                         // bytes (= elems) of K per phase
#define NPHASE (DIM / BK)              // 8
#define NT     (N_ROWS / BM)           // 32
#define NTILES (NT * (NT + 1) / 2)     // 528 = 8 * 66
#define OFFS   14.4269504088896340f    // 10 * log2e
#define ROW_SCALE 3.7982825605f        // sqrt(10 * log2e)
#define LN2    0.6931471805599453f
#define LOGIT_MAX 10.0f
#define SCALE1 0x7F7F7F7F              // e8m0 1.0 in every byte

typedef float floatx4 __attribute__((ext_vector_type(4)));
typedef int   intx4   __attribute__((ext_vector_type(4)));
typedef int   intx8   __attribute__((ext_vector_type(8)));

__device__ __forceinline__ void async_copy16(const void* g, void* lds) {
  __builtin_amdgcn_global_load_lds(
      (const __attribute__((address_space(1))) void*)g,
      (__attribute__((address_space(3))) void*)lds, 16, 0, 0);
}

__device__ __forceinline__ unsigned pack4_e4m3(float a, float b, float c, float d) {
  __hip_fp8_e4m3 qa(a), qb(b), qc(c), qd(d);
  return (unsigned)qa.__x | ((unsigned)qb.__x << 8) |
         ((unsigned)qc.__x << 16) | ((unsigned)qd.__x << 24);
}

// ---------------- Kernel 1: row normalize -> fp8 (+ zero accumulators) ----
__global__ __launch_bounds__(256) void normalize_kernel(
    const float* __restrict__ z, unsigned char* __restrict__ zn,
    float* __restrict__ sumexp, float* __restrict__ out) {
  const int tid = threadIdx.x, wave = tid >> 6, lane = tid & 63;
  const int row = blockIdx.x * 4 + wave;

  if (blockIdx.x < 8) ((float4*)sumexp)[blockIdx.x * 256 + tid] = float4{0, 0, 0, 0};
  if (blockIdx.x == 8 && tid == 0) out[0] = 0.0f;

  const float4* zr = (const float4*)(z + (size_t)row * DIM);
  float4 v[4];
  #pragma unroll
  for (int j = 0; j < 4; j++) v[j] = zr[lane + 64 * j];
  float ss = 0.0f;
  #pragma unroll
  for (int j = 0; j < 4; j++)
    ss += v[j].x * v[j].x + v[j].y * v[j].y + v[j].z * v[j].z + v[j].w * v[j].w;
  #pragma unroll
  for (int off = 32; off > 0; off >>= 1) ss += __shfl_xor(ss, off);
  const float scale = rsqrtf(ss) * ROW_SCALE;  // norms ~32 >> eps

  unsigned* o = (unsigned*)(zn + (size_t)row * DIM);
  #pragma unroll
  for (int j = 0; j < 4; j++)
    o[lane + 64 * j] = pack4_e4m3(v[j].x * scale, v[j].y * scale,
                                  v[j].z * scale, v[j].w * scale);
}

// Supercell-major decode over the 32x32 supertile triangle: 4x4 supercells
// (8 cell-rows). Diag cell = 10 tiles (upper-tri 4x4), off-diag = 16.
// Cell-row SI prefix P(SI) = 130*SI - 8*SI*SI (P(8)=528). Within a row:
// diag cell first, then snake over off-diag cells (even SI ascending, odd
// descending); within cell row-major. Concurrent window/XCD (~32 blocks at
// 1 block/CU) spans ~2 cells = <=3MB of panels -> fits 4MB XCD L2.
__device__ __forceinline__ void decode_tile(int g, int& I, int& J) {
  int SI = 0;
  #pragma unroll
  for (int s = 1; s < 8; ++s)
    if (130 * s - 8 * s * s <= g) SI = s;
  int rem = g - (130 * SI - 8 * SI * SI);
  int i, j, SJ;
  if (rem < 10) {                       // diagonal supercell, upper-tri 4x4
    SJ = SI;
    i = 0;
    while ((i + 1) * (9 - (i + 1)) / 2 <= rem) ++i;  // prefix(i)=i*(9-i)/2
    j = i + (rem - i * (9 - i) / 2);
  } else {                              // full off-diagonal supercell
    const int rem2 = rem - 10;
    const int cc = rem2 >> 4;           // 0 .. (6-SI)
    const int k  = rem2 & 15;
    SJ = (SI & 1) ? (7 - cc) : (SI + 1 + cc);
    i = k >> 2;
    j = k & 3;
  }
  I = SI * 4 + i;
  J = SJ * 4 + j;
}

// ---------------- Kernel 2: upper-tri MX-fp8 GEMM + partial sum-exp -------
__global__ __launch_bounds__(512, 2) void fused_gemm_lse(
    const unsigned char* __restrict__ zn, float* __restrict__ sumexp,
    float* __restrict__ pos) {
  __shared__ unsigned char sA[2][BM * BK];    // 2 x 32 KB (double buffer)
  __shared__ unsigned char sB[2][BM * BK];    // 2 x 32 KB (double buffer)
  __shared__ float rowRed[4][BM];             // 4 KB
  __shared__ float colRed[2][BM];             // 2 KB   (total 134 KB)

  const int tid  = threadIdx.x;               // 0..511
  const int lane = tid & 63;
  const int wave = tid >> 6;                  // 0..7
  const int quad = lane >> 4;
  const int l15  = lane & 15;
  const int waveM = wave >> 2;  // 0..1  (128-row half)
  const int waveN = wave & 3;   // 0..3  (64-col quarter)

  // XCD-contiguous tile permutation (528 = 8 * 66)
  const int t = (blockIdx.x & 7) * (NTILES / 8) + (blockIdx.x >> 3);
  int I, J;
  decode_tile(t, I, J);
  const int rowBase = I * BM, colBase = J * BM;

  // staging: 256x128B tile = 2048 16B-chunks, 4/thread/matrix.
  // chunk s: row r = s>>3, stored slot s&7 holds logical 16B k-chunk
  // q = (s&7) ^ (r&7)  (XOR swizzle, applied on the global-address side).
  int rOff[4], soff[4];
  #pragma unroll
  for (int i = 0; i < 4; i++) {
    const int s = i * 512 + tid;            // 0..2047
    const int r = s >> 3;                   // tile row 0..255
    const int q = (s & 7) ^ (r & 7);        // logical k-chunk 0..7
    rOff[i] = r * DIM + q * 16;
    soff[i] = s * 16;                       // wave-uniform base + lane*16
  }
  auto stage = [&](int buf, int p) {
    const unsigned char* ga = zn + (size_t)rowBase * DIM + p * BK;
    const unsigned char* gb = zn + (size_t)colBase * DIM + p * BK;
    #pragma unroll
    for (int i = 0; i < 4; i++)
      async_copy16(ga + rOff[i], (char*)sA[buf] + soff[i]);
    #pragma unroll
    for (int i = 0; i < 4; i++)
      async_copy16(gb + rOff[i], (char*)sB[buf] + soff[i]);
  };

  floatx4 acc[8][4];
  #pragma unroll
  for (int mi = 0; mi < 8; mi++)
    #pragma unroll
    for (int ni = 0; ni < 4; ni++) acc[mi][ni] = {0.f, 0.f, 0.f, 0.f};

  stage(0, 0);                          // only cold fill

  for (int p = 0; p < NPHASE; ++p) {
    const int b = p & 1;
    __syncthreads();                    // phase p staged (vmcnt+lgkm drain)
    if (p + 1 < NPHASE) stage(b ^ 1, p + 1);   // async prefetch

    intx8 bb[4];
    #pragma unroll
    for (int ni = 0; ni < 4; ni++) {
      const int r = waveN * 64 + ni * 16 + l15;       // tile col 0..255
      const int c0 = (quad * 2) ^ (r & 7);
      const intx4 lo = *(const intx4*)(&sB[b][0] + (r * 8 + c0) * 16);
      const intx4 hi = *(const intx4*)(&sB[b][0] + (r * 8 + (c0 ^ 1)) * 16);
      bb[ni] = __builtin_shufflevector(lo, hi, 0, 1, 2, 3, 4, 5, 6, 7);
    }
    #pragma unroll
    for (int mi = 0; mi < 8; mi++) {
      const int r = waveM * 128 + mi * 16 + l15;      // tile row 0..255
      const int c0 = (quad * 2) ^ (r & 7);
      const intx4 lo = *(const intx4*)(&sA[b][0] + (r * 8 + c0) * 16);
      const intx4 hi = *(const intx4*)(&sA[b][0] + (r * 8 + (c0 ^ 1)) * 16);
      const intx8 a = __builtin_shufflevector(lo, hi, 0, 1, 2, 3, 4, 5, 6, 7);
      #pragma unroll
      for (int ni = 0; ni < 4; ni++)
        acc[mi][ni] = __builtin_amdgcn_mfma_scale_f32_16x16x128_f8f6f4(
            a, bb[ni], acc[mi][ni],
            0 /*cbsz: A=e4m3*/, 0 /*blgp: B=e4m3*/,
            0, SCALE1,   // opsel_a, scale_a = 1.0
            0, SCALE1);  // opsel_b, scale_b = 1.0
    }
  }

  // ---- epilogue ----
  // C/D layout (16x16 family): col = l15, row = quad*4 + reg
  // local row = waveM*128 + mi*16 + quad*4 + r; local col = waveN*64 + ni*16 + l15
  const bool diagBlk = (I == J);

  if (J == I + 16) {  // positive-pair supertile (col = row + 4096)
    #pragma unroll
    for (int mi = 0; mi < 8; mi++)
      #pragma unroll
      for (int ni = 0; ni < 4; ni++)
        #pragma unroll
        for (int r = 0; r < 4; r++) {
          const int lrow = waveM * 128 + mi * 16 + quad * 4 + r;
          const int lcol = waveN * 64 + ni * 16 + l15;
          if (lrow == lcol) pos[rowBase + lrow] = acc[mi][ni][r];
        }
  }

  float rsum[8][4], csum[4];
  #pragma unroll
  for (int mi = 0; mi < 8; mi++)
    #pragma unroll
    for (int r = 0; r < 4; r++) rsum[mi][r] = 0.0f;
  #pragma unroll
  for (int ni = 0; ni < 4; ni++) csum[ni] = 0.0f;

  if (diagBlk) {
    #pragma unroll
    for (int mi = 0; mi < 8; mi++)
      #pragma unroll
      for (int ni = 0; ni < 4; ni++)
        #pragma unroll
        for (int r = 0; r < 4; r++) {
          const int lrow = waveM * 128 + mi * 16 + quad * 4 + r;
          const int lcol = waveN * 64 + ni * 16 + l15;
          float e = exp2f(acc[mi][ni][r] - OFFS);
          if (lrow == lcol) e = 0.0f;         // masked diagonal
          rsum[mi][r] += e;
        }
  } else {
    #pragma unroll
    for (int mi = 0; mi < 8; mi++)
      #pragma unroll
      for (int ni = 0; ni < 4; ni++)
        #pragma unroll
        for (int r = 0; r < 4; r++) {
          const float e = exp2f(acc[mi][ni][r] - OFFS);
          rsum[mi][r] += e;
          csum[ni]    += e;
        }
  }

  // row sums: reduce over the 16 cols (l15) of each fragment row
  #pragma unroll
  for (int mi = 0; mi < 8; mi++)
    #pragma unroll
    for (int r = 0; r < 4; r++) {
      float v = rsum[mi][r];
      v += __shfl_xor(v, 1);
      v += __shfl_xor(v, 2);
      v += __shfl_xor(v, 4);
      v += __shfl_xor(v, 8);
      if (l15 == 0)
        rowRed[waveN][waveM * 128 + mi * 16 + quad * 4 + r] = v;
    }
  // col sums: csum already folded mi,r; fold the 4 quads
  if (!diagBlk) {
    #pragma unroll
    for (int ni = 0; ni < 4; ni++) {
      float v = csum[ni];
      v += __shfl_xor(v, 16);
      v += __shfl_xor(v, 32);
      if (quad == 0)
        colRed[waveM][waveN * 64 + ni * 16 + l15] = v;
    }
  }
  __syncthreads();

  if (tid < BM) {
    atomicAdd(&sumexp[rowBase + tid],
              rowRed[0][tid] + rowRed[1][tid] + rowRed[2][tid] + rowRed[3][tid]);
  } else if (!diagBlk) {
    const int c = tid - BM;
    atomicAdd(&sumexp[colBase + c], colRed[0][c] + colRed[1][c]);
  }
}

// ---------------- Kernel 3: mean NLL --------------------------------------
__global__ __launch_bounds__(256) void finalize_kernel(
    const float* __restrict__ sumexp, const float* __restrict__ pos,
    float* __restrict__ out) {
  const int tid = threadIdx.x;
  const int row = blockIdx.x * 256 + tid;
  // pos holds d = logit*log2e for rows [0,4096); pos[i+4096] == pos[i]
  float local = -(pos[row & (N_ROWS / 2 - 1)] * LN2) + LOGIT_MAX + logf(sumexp[row]);
  #pragma unroll
  for (int off = 32; off > 0; off >>= 1) local += __shfl_xor(local, off);
  __shared__ float red[4];
  const int wave = tid >> 6, lane = tid & 63;
  if (lane == 0) red[wave] = local;
  __syncthreads();
  if (tid == 0)
    atomicAdd(out, (red[0] + red[1] + red[2] + red[3]) * (1.0f / N_ROWS));
}

extern "C" void kernel_launch(void* const* d_in, const int* in_sizes, int n_in,
                              void* d_out, int out_size, void* d_ws, size_t ws_size,
                              hipStream_t stream) {
  const float* z = (const float*)d_in[0];
  float* out = (float*)d_out;

  char* ws = (char*)d_ws;
  unsigned char* zn = (unsigned char*)ws;                    // 8 MB fp8
  float* sumexp = (float*)(ws + (size_t)N_ROWS * DIM);       // 32 KB
  float* pos    = sumexp + N_ROWS;                           // 16 KB

  normalize_kernel<<<N_ROWS / 4, 256, 0, stream>>>(z, zn, sumexp, out);
  fused_gemm_lse<<<NTILES, 512, 0, stream>>>(zn, sumexp, pos);
  finalize_kernel<<<N_ROWS / 256, 256, 0, stream>>>(sumexp, pos, out);
}